// Round 14
// baseline (236.846 us; speedup 1.0000x reference)
//
#include <hip/hip_runtime.h>
#include <hip/hip_fp16.h>

using i32x4  = __attribute__((ext_vector_type(4)))  int;
using i32x16 = __attribute__((ext_vector_type(16))) int;

static constexpr int M  = 4 * 2048;   // 8192 rows (B*S)
static constexpr int N  = 4096;       // OUT_F
static constexpr int K  = 4096;       // IN_F
static constexpr int BM = 256, BN = 256, BK = 64;
static constexpr int NT = K / BK;         // 64 K-tiles
static constexpr int ATILE = BM * BK;     // 16384 B packed A tile (256-row)
static constexpr int BTILE = 128 * BK;    //  8192 B packed B tile (128-col panels)

// ---------------- fused pack kernel: int32 -> blocked int8 tiles -------------
// A tile (16 KB): [kg(4)][row(256)][16B]   wa: [M/256][NT][ATILE]
// B tile ( 8 KB): [kg(4)][col(128)][16B]   wb: [N/128][NT][BTILE] (transposed)
static constexpr int PX_BLOCKS = (int)((size_t)M * K / 16 / 256);  // 8192
static constexpr int PW_BLOCKS = (int)((size_t)N * K / 16 / 256);  // 4096

__device__ __forceinline__ unsigned pack4(i32x4 v) {
  return (unsigned)((v.x & 255) | ((v.y & 255) << 8) | ((v.z & 255) << 16) | (v.w << 24));
}

__global__ __launch_bounds__(256) void pack_kernel(const int* __restrict__ x,
                                                   const int* __restrict__ w,
                                                   unsigned char* __restrict__ wa,
                                                   unsigned char* __restrict__ wb) {
  if (blockIdx.x < PX_BLOCKS) {
    unsigned g = blockIdx.x * 256 + threadIdx.x;   // dest 16B granule, < M*K/16
    unsigned row = g & 255;
    unsigned kg  = (g >> 8) & 3;
    unsigned kt  = (g >> 10) & 63;
    unsigned br  = g >> 16;
    const int* src = x + ((size_t)(br * 256 + row) * K + kt * 64 + kg * 16);
    i32x4 v0 = *(const i32x4*)(src + 0);
    i32x4 v1 = *(const i32x4*)(src + 4);
    i32x4 v2 = *(const i32x4*)(src + 8);
    i32x4 v3 = *(const i32x4*)(src + 12);
    i32x4 d;
    d.x = (int)pack4(v0); d.y = (int)pack4(v1); d.z = (int)pack4(v2); d.w = (int)pack4(v3);
    *(i32x4*)(wa + (size_t)g * 16) = d;
  } else {
    unsigned g = (blockIdx.x - PX_BLOCKS) * 256 + threadIdx.x;  // < N*K/16
    unsigned col = g & 127;
    unsigned kg  = (g >> 7) & 3;
    unsigned kt  = (g >> 9) & 63;
    unsigned bn  = g >> 15;
    unsigned n   = bn * 128 + col;
    unsigned k0  = kt * 64 + kg * 16;
    const int* src = w + (size_t)k0 * N + n;
    i32x4 d;
#pragma unroll
    for (int j = 0; j < 4; ++j) {
      int b0 = src[(size_t)(j * 4 + 0) * N];
      int b1 = src[(size_t)(j * 4 + 1) * N];
      int b2 = src[(size_t)(j * 4 + 2) * N];
      int b3 = src[(size_t)(j * 4 + 3) * N];
      d[j] = (b0 & 255) | ((b1 & 255) << 8) | ((b2 & 255) << 16) | (b3 << 24);
    }
    *(i32x4*)(wb + (size_t)g * 16) = d;
  }
}

// -- GEMM: 256x256, 8 waves (4x2, wave 64x128, acc[2][4]), A via LDS dbuf -----
// (reg-staged, distance 2), B direct L2->VGPR. RAW s_barrier + lgkmcnt(0) only:
// vmcnt is NEVER drained mid-loop, so A(t+2)/B(t+1) loads span barriers.

#define SBAR()  do { __builtin_amdgcn_sched_barrier(0);                         \
                     asm volatile("s_waitcnt lgkmcnt(0)" ::: "memory");         \
                     __builtin_amdgcn_s_barrier();                              \
                     __builtin_amdgcn_sched_barrier(0); } while (0)

__global__ __launch_bounds__(512) void gemm_i8(const unsigned char* __restrict__ wa,
                                               const unsigned char* __restrict__ wb,
                                               const __half* __restrict__ bias,
                                               const float* __restrict__ alphaP,
                                               float* __restrict__ out) {
  __shared__ __align__(16) unsigned char As[2][ATILE];   // 32 KB (A only)

  const int tid  = threadIdx.x;
  const int lane = tid & 63;
  const int w    = tid >> 6;            // wave 0..7
  const int wr   = w >> 1, wc = w & 1;  // 4 x 2 grid; wave tile 64 x 128
  const int l31  = lane & 31;
  const int kgl  = lane >> 5;

  // XCD-chunk swizzle (bijective: 512 % 8 == 0, chunk 64): each XCD works
  // br in {4k..4k+3} x all bc -> 4 A panels (4 MB) L2-resident per XCD.
  const int bid = blockIdx.x;
  const int swz = (bid & 7) * 64 + (bid >> 3);
  const int bc  = swz & 15;             // 0..15 (N/256)
  const int br  = swz >> 4;             // 0..31 (M/256)

  const unsigned char* ga  = wa + (size_t)br * NT * ATILE;
  // per-wave B panel: global cols [bc*256 + wc*128, +128) = packed panel bc*2+wc
  const unsigned char* gbp = wb + (size_t)(bc * 2 + wc) * NT * BTILE;

  const int arow = wr * 64 + l31;       // A frag row base (per lane)
  const int bcl  = l31;                 // within-panel col base

  // A staging sets (distance 2): P = even tiles, Q = odd tiles (2 x 16B each)
  i32x4 p0, p1, q0, q1;
  // B regs: [kc][ni] single set, reloaded per-kc right after last use
  i32x4 b[2][4];

#define GLOADA_P(T) do {                                             \
    const i32x4* ap = (const i32x4*)(ga + (size_t)(T) * ATILE);      \
    p0 = ap[tid]; p1 = ap[tid + 512];                                \
  } while (0)

#define GLOADA_Q(T) do {                                             \
    const i32x4* ap = (const i32x4*)(ga + (size_t)(T) * ATILE);      \
    q0 = ap[tid]; q1 = ap[tid + 512];                                \
  } while (0)

#define SWRITE_P(BUF) do {                                           \
    i32x4* aw = (i32x4*)&As[BUF][0];                                 \
    aw[tid] = p0; aw[tid + 512] = p1;                                \
  } while (0)

#define SWRITE_Q(BUF) do {                                           \
    i32x4* aw = (i32x4*)&As[BUF][0];                                 \
    aw[tid] = q0; aw[tid + 512] = q1;                                \
  } while (0)

#define BLOAD(KC, T) do {                                            \
    const unsigned char* bt = gbp + (size_t)(T) * BTILE + ((KC) * 2 + kgl) * 2048; \
    b[KC][0] = *(const i32x4*)(bt + (bcl +  0) * 16);                \
    b[KC][1] = *(const i32x4*)(bt + (bcl + 32) * 16);                \
    b[KC][2] = *(const i32x4*)(bt + (bcl + 64) * 16);                \
    b[KC][3] = *(const i32x4*)(bt + (bcl + 96) * 16);                \
  } while (0)

  i32x16 acc[2][4] = {};

#define MFMA8(KC, A0, A1)                                                        \
    acc[0][0] = __builtin_amdgcn_mfma_i32_32x32x32_i8(A0, b[KC][0], acc[0][0], 0,0,0); \
    acc[0][1] = __builtin_amdgcn_mfma_i32_32x32x32_i8(A0, b[KC][1], acc[0][1], 0,0,0); \
    acc[0][2] = __builtin_amdgcn_mfma_i32_32x32x32_i8(A0, b[KC][2], acc[0][2], 0,0,0); \
    acc[0][3] = __builtin_amdgcn_mfma_i32_32x32x32_i8(A0, b[KC][3], acc[0][3], 0,0,0); \
    acc[1][0] = __builtin_amdgcn_mfma_i32_32x32x32_i8(A1, b[KC][0], acc[1][0], 0,0,0); \
    acc[1][1] = __builtin_amdgcn_mfma_i32_32x32x32_i8(A1, b[KC][1], acc[1][1], 0,0,0); \
    acc[1][2] = __builtin_amdgcn_mfma_i32_32x32x32_i8(A1, b[KC][2], acc[1][2], 0,0,0); \
    acc[1][3] = __builtin_amdgcn_mfma_i32_32x32x32_i8(A1, b[KC][3], acc[1][3], 0,0,0)

#define STEP(T, PARITY) do {                                                   \
    if ((T) + 2 < NT) { if (PARITY) GLOADA_Q((T) + 2); else GLOADA_P((T) + 2); } \
    const unsigned char* Ab = &As[(T) & 1][0];                                 \
    { /* kc0 */                                                                \
      const unsigned char* Ap = Ab + kgl * 4096;                               \
      i32x4 a0 = *(const i32x4*)(Ap + (arow +  0) * 16);                       \
      i32x4 a1 = *(const i32x4*)(Ap + (arow + 32) * 16);                       \
      MFMA8(0, a0, a1);                                                        \
    }                                                                          \
    if ((T) + 1 < NT) BLOAD(0, (T) + 1);  /* b[0] free after kc0 MFMAs */      \
    { /* kc1 */                                                                \
      const unsigned char* Ap = Ab + (2 + kgl) * 4096;                         \
      i32x4 a0 = *(const i32x4*)(Ap + (arow +  0) * 16);                       \
      i32x4 a1 = *(const i32x4*)(Ap + (arow + 32) * 16);                       \
      MFMA8(1, a0, a1);                                                        \
    }                                                                          \
    if ((T) + 1 < NT) BLOAD(1, (T) + 1);                                       \
    __builtin_amdgcn_sched_barrier(0);                                         \
    if ((T) + 1 < NT) {                                                        \
      /* write tile T+1 (loaded at T-1): compiler emits COUNTED vmcnt */       \
      if (PARITY) SWRITE_P(((T) & 1) ^ 1); else SWRITE_Q(((T) & 1) ^ 1);       \
      SBAR();                                                                  \
    }                                                                          \
  } while (0)

  // prologue: A(0)->LDS buf0, A(1) in flight (Q), B(0) resident
  GLOADA_P(0);
  BLOAD(0, 0);
  BLOAD(1, 0);
  SWRITE_P(0);
  GLOADA_Q(1);
  __syncthreads();    // one full drain before the loop is fine

  for (int t = 0; t < NT; t += 2) {
    STEP(t, 0);       // even: prefetch A into P, write Q (tile t+1)
    STEP(t + 1, 1);   // odd:  prefetch A into Q, write P (tile t+2)
  }

  // epilogue: C/D layout col=lane&31, row=(r&3)+8*(r>>2)+4*(lane>>5)
  const float alpha = *alphaP;
  const int row0 = br * 256 + wr * 64 + 4 * kgl;
  const int col0 = bc * 256 + wc * 128 + l31;
#pragma unroll
  for (int ni = 0; ni < 4; ++ni) {
    const int col = col0 + ni * 32;
    const float bf = __half2float(bias[col]);
#pragma unroll
    for (int mi = 0; mi < 2; ++mi) {
#pragma unroll
      for (int r = 0; r < 16; ++r) {
        const int row = row0 + mi * 32 + (r & 3) + 8 * (r >> 2);
        out[(size_t)row * N + col] = ((float)acc[mi][ni][r] + bf) * alpha;
      }
    }
  }
#undef STEP
#undef MFMA8
#undef GLOADA_P
#undef GLOADA_Q
#undef SWRITE_P
#undef SWRITE_Q
#undef BLOAD
}

extern "C" void kernel_launch(void* const* d_in, const int* in_sizes, int n_in,
                              void* d_out, int out_size, void* d_ws, size_t ws_size,
                              hipStream_t stream) {
  const int*    x     = (const int*)d_in[0];
  const int*    wgt   = (const int*)d_in[1];
  const __half* bias  = (const __half*)d_in[2];
  const float*  alpha = (const float*)d_in[3];
  float*        out   = (float*)d_out;

  // workspace: packed A (32 MB) + packed B (16 MB) = 48 MB
  unsigned char* wa = (unsigned char*)d_ws;
  unsigned char* wb = wa + (size_t)M * K;

  pack_kernel<<<PX_BLOCKS + PW_BLOCKS, 256, 0, stream>>>(x, wgt, wa, wb);

  dim3 grid((M / BM) * (N / BN));   // 512 blocks, 512 threads
  gemm_i8<<<grid, 512, 0, stream>>>(wa, wb, bias, alpha, out);
}